// Round 5
// baseline (243.227 us; speedup 1.0000x reference)
//
#include <hip/hip_runtime.h>

// Windowed MHA, B=16 C=128 H=W=128, WINDOW=64, heads=4, d=32.
// 2048 blocks x 512 threads; each block does TWO adjacent windows (prefetched).
// Wave = (head w, token-half h). bf16 MFMA 16x16x32, swapped QK^T.
// P redistribution QK^T-D-layout -> PV-A-fragment done in-register via
// ds_bpermute (no P LDS buffer, no barrier). Swizzle f(row) chosen so both
// staging writes AND fragment reads are conflict-free (R4 had 8-way on staging).

typedef __attribute__((ext_vector_type(8))) short bf16x8;
typedef __attribute__((ext_vector_type(4))) float f32x4;

__device__ __forceinline__ ushort f2bf(float f) {
    unsigned u = __float_as_uint(f);
    u += 0x7FFF + ((u >> 16) & 1);          // RNE
    return (ushort)(u >> 16);
}
__device__ __forceinline__ unsigned pk2(float a, float b) {
    return (unsigned)f2bf(a) | ((unsigned)f2bf(b) << 16);
}
// 256B-row tiles (sX/sQ/sK): spreads row bits 0-3 XOR row bits 4-5 into byte bits 4-7.
__device__ __forceinline__ int fsw(int row) { return ((row ^ (row >> 4)) & 15) << 4; }
// 128B-row tiles (sVt): byte bits 4-6.
__device__ __forceinline__ int gsw(int row) { return ((row ^ (row >> 3)) & 7) << 4; }

__global__ void wconv(const float* __restrict__ Wq, const float* __restrict__ Wk,
                      const float* __restrict__ Wv, ushort* __restrict__ out) {
    int i = blockIdx.x * 256 + threadIdx.x;        // 16384 per matrix
    out[i]         = f2bf(Wq[i]);
    out[16384 + i] = f2bf(Wk[i]);
    out[32768 + i] = f2bf(Wv[i]);
}

__global__ __launch_bounds__(512, 4)
void attn_win(const float* __restrict__ x, const ushort* __restrict__ wbf,
              const float* __restrict__ bq, const float* __restrict__ bk,
              const float* __restrict__ bv, const float* __restrict__ Bb,
              float* __restrict__ out) {
    __shared__ __align__(16) char smem[49152];
    // R0 [0,16K): sX (staging) -> sVt (V transposed) after Ba
    // R1 [16K,32K): sQ   R2 [32K,48K): sK
    char* sX  = smem;
    char* sVt = smem;
    char* sQ  = smem + 16384;
    char* sK  = smem + 32768;

    const int tid = threadIdx.x;
    const int wid = tid >> 6;        // 0..7
    const int w = wid & 3;           // head
    const int h = wid >> 2;          // token half (0..1)
    const int l = tid & 63;
    const int lr = l & 15;
    const int lg = (l >> 4) & 3;
    const int blk = blockIdx.x;
    const int b = blk >> 7, np = blk & 127;
    const long xbase0 = (long)b * 128 * 16384 + (long)(2 * np) * 64;

    // lane plumbing for the in-register P redistribution
    const int srcA = ((l & 16) << 1) | (l & 15);   // lane holding lg' = 2*(lg&1)
    const int srcB = srcA | 16;                    // lg' = 2*(lg&1)+1
    const bool hi = (l >= 32);                     // lg>>1: selects tm = 2kk+1

    // ---- prefetch BOTH windows' X into registers (issued together, adjacent) ----
    float4 pf[2][4];
    #pragma unroll
    for (int wi = 0; wi < 2; ++wi)
        #pragma unroll
        for (int it = 0; it < 2; ++it) {
            int idx = it * 512 + tid;
            int cp = idx >> 4, t4 = idx & 15;
            const float* px = x + xbase0 + wi * 64 + (long)(2 * cp) * 16384 + t4 * 4;
            pf[wi][it * 2 + 0] = *(const float4*)(px);
            pf[wi][it * 2 + 1] = *(const float4*)(px + 16384);
        }

    #pragma unroll
    for (int wi = 0; wi < 2; ++wi) {
        const long xb = xbase0 + wi * 64;

        // ---- stage X: fp32 pair -> packed bf16x2 ds_write_b32, conflict-free ----
        #pragma unroll
        for (int it = 0; it < 2; ++it) {
            int idx = it * 512 + tid;
            int cp = idx >> 4, t4 = idx & 15;
            float4 v0 = pf[wi][it * 2 + 0];
            float4 v1 = pf[wi][it * 2 + 1];
            float a0[4] = {v0.x, v0.y, v0.z, v0.w};
            float a1[4] = {v1.x, v1.y, v1.z, v1.w};
            #pragma unroll
            for (int jj = 0; jj < 4; ++jj) {
                int t = t4 * 4 + jj;
                *(unsigned*)(sX + t * 256 + ((4 * cp) ^ fsw(t))) = pk2(a0[jj], a1[jj]);
            }
        }
        __syncthreads();   // B1

        // ---- A-fragments of X (this wave's 32 tokens) ----
        bf16x8 aX[2][4];
        #pragma unroll
        for (int tmi = 0; tmi < 2; ++tmi) {
            int row = 32 * h + 16 * tmi + lr;
            #pragma unroll
            for (int kk = 0; kk < 4; ++kk) {
                int colb = (8 * lg + 32 * kk) * 2;
                aX[tmi][kk] = *(const bf16x8*)(sX + row * 256 + (colb ^ fsw(row)));
            }
        }

        // ---- Q,K projections ----
        #pragma unroll
        for (int p = 0; p < 2; ++p) {
            const ushort* wp = wbf + p * 16384;
            const float* bias_p = (p == 0) ? bq : bk;
            f32x4 acc[2][2];
            #pragma unroll
            for (int tn = 0; tn < 2; ++tn) {
                float bias = bias_p[32 * w + 16 * tn + lr];
                #pragma unroll
                for (int tmi = 0; tmi < 2; ++tmi)
                    acc[tmi][tn] = (f32x4){bias, bias, bias, bias};
            }
            #pragma unroll
            for (int kk = 0; kk < 4; ++kk) {
                bf16x8 bW[2];
                #pragma unroll
                for (int tn = 0; tn < 2; ++tn)
                    bW[tn] = *(const bf16x8*)(wp + (32 * w + 16 * tn + lr) * 128 + 8 * lg + 32 * kk);
                #pragma unroll
                for (int tmi = 0; tmi < 2; ++tmi)
                    #pragma unroll
                    for (int tn = 0; tn < 2; ++tn)
                        acc[tmi][tn] = __builtin_amdgcn_mfma_f32_16x16x32_bf16(
                            aX[tmi][kk], bW[tn], acc[tmi][tn], 0, 0, 0);
            }
            char* dst = (p == 0) ? sQ : sK;
            #pragma unroll
            for (int tmi = 0; tmi < 2; ++tmi)
                #pragma unroll
                for (int tn = 0; tn < 2; ++tn)
                    #pragma unroll
                    for (int r = 0; r < 4; ++r) {
                        int row = 32 * h + 16 * tmi + 4 * lg + r;
                        int col = 32 * w + 16 * tn + lr;
                        *(ushort*)(dst + row * 256 + ((col * 2) ^ fsw(row)))
                            = f2bf(acc[tmi][tn][r]);
                    }
        }
        __syncthreads();   // Ba: aX reads done (sX reusable as sVt); sQ/sK complete

        // ---- V projection -> sVt[c][tok] (aliases sX), packed b64, g-swizzle ----
        {
            const ushort* wp = wbf + 32768;
            f32x4 acc[2][2];
            #pragma unroll
            for (int tn = 0; tn < 2; ++tn) {
                float bias = bv[32 * w + 16 * tn + lr];
                #pragma unroll
                for (int tmi = 0; tmi < 2; ++tmi)
                    acc[tmi][tn] = (f32x4){bias, bias, bias, bias};
            }
            #pragma unroll
            for (int kk = 0; kk < 4; ++kk) {
                bf16x8 bW[2];
                #pragma unroll
                for (int tn = 0; tn < 2; ++tn)
                    bW[tn] = *(const bf16x8*)(wp + (32 * w + 16 * tn + lr) * 128 + 8 * lg + 32 * kk);
                #pragma unroll
                for (int tmi = 0; tmi < 2; ++tmi)
                    #pragma unroll
                    for (int tn = 0; tn < 2; ++tn)
                        acc[tmi][tn] = __builtin_amdgcn_mfma_f32_16x16x32_bf16(
                            aX[tmi][kk], bW[tn], acc[tmi][tn], 0, 0, 0);
            }
            #pragma unroll
            for (int tmi = 0; tmi < 2; ++tmi)
                #pragma unroll
                for (int tn = 0; tn < 2; ++tn) {
                    int crow = 32 * w + 16 * tn + lr;
                    int tok0 = 32 * h + 16 * tmi + 4 * lg;
                    uint2 pk;
                    pk.x = pk2(acc[tmi][tn][0], acc[tmi][tn][1]);
                    pk.y = pk2(acc[tmi][tn][2], acc[tmi][tn][3]);
                    *(uint2*)(sVt + crow * 128 + ((2 * tok0) ^ gsw(crow))) = pk;
                }
        }

        // ---- scores^T = mfma(A=K, B=Q): D[k=16tm+4lg+r][q=32h+16tq+lr] ----
        bf16x8 aK[4], bQ[2];
        const int colqk = (32 * w + 8 * lg) * 2;
        #pragma unroll
        for (int tm = 0; tm < 4; ++tm) {
            int row = 16 * tm + lr;
            aK[tm] = *(const bf16x8*)(sK + row * 256 + (colqk ^ fsw(row)));
        }
        #pragma unroll
        for (int tq = 0; tq < 2; ++tq) {
            int row = 32 * h + 16 * tq + lr;
            bQ[tq] = *(const bf16x8*)(sQ + row * 256 + (colqk ^ fsw(row)));
        }
        f32x4 sc[4][2];
        #pragma unroll
        for (int tm = 0; tm < 4; ++tm)
            #pragma unroll
            for (int tq = 0; tq < 2; ++tq) {
                sc[tm][tq] = (f32x4){0.f, 0.f, 0.f, 0.f};
                sc[tm][tq] = __builtin_amdgcn_mfma_f32_16x16x32_bf16(
                    aK[tm], bQ[tq], sc[tm][tq], 0, 0, 0);
            }

        // ---- softmax (k in-lane: 16 vals) + normalize at source ----
        const float scale = 0.17677669529663687f;   // 1/sqrt(32)
        const float L2E = 1.4426950408889634f;
        #pragma unroll
        for (int tq = 0; tq < 2; ++tq) {
            int q = 32 * h + 16 * tq + lr;
            #pragma unroll
            for (int tm = 0; tm < 4; ++tm) {
                float4 bb = *(const float4*)(Bb + q * 64 + 16 * tm + 4 * lg);
                sc[tm][tq][0] = sc[tm][tq][0] * scale + bb.x;
                sc[tm][tq][1] = sc[tm][tq][1] * scale + bb.y;
                sc[tm][tq][2] = sc[tm][tq][2] * scale + bb.z;
                sc[tm][tq][3] = sc[tm][tq][3] * scale + bb.w;
            }
            float mx = sc[0][tq][0];
            #pragma unroll
            for (int tm = 0; tm < 4; ++tm)
                #pragma unroll
                for (int r = 0; r < 4; ++r)
                    mx = fmaxf(mx, sc[tm][tq][r]);
            mx = fmaxf(mx, __shfl_xor(mx, 16));
            mx = fmaxf(mx, __shfl_xor(mx, 32));
            float s = 0.f;
            #pragma unroll
            for (int tm = 0; tm < 4; ++tm)
                #pragma unroll
                for (int r = 0; r < 4; ++r) {
                    float e = exp2f((sc[tm][tq][r] - mx) * L2E);
                    sc[tm][tq][r] = e;
                    s += e;
                }
            s += __shfl_xor(s, 16);
            s += __shfl_xor(s, 32);
            float rs = 1.0f / s;
            #pragma unroll
            for (int tm = 0; tm < 4; ++tm)
                #pragma unroll
                for (int r = 0; r < 4; ++r)
                    sc[tm][tq][r] *= rs;
        }
        __syncthreads();   // Bb: sVt fully written before PV reads

        // ---- pack P rows to bf16 pairs: pks[tm][tq][half] ----
        unsigned pks[4][2][2];
        #pragma unroll
        for (int tm = 0; tm < 4; ++tm)
            #pragma unroll
            for (int tq = 0; tq < 2; ++tq) {
                pks[tm][tq][0] = pk2(sc[tm][tq][0], sc[tm][tq][1]);
                pks[tm][tq][1] = pk2(sc[tm][tq][2], sc[tm][tq][3]);
            }

        // ---- out = P.V : aP built via ds_bpermute (no LDS, no barrier) ----
        f32x4 o[2][2];
        #pragma unroll
        for (int tm2 = 0; tm2 < 2; ++tm2)
            #pragma unroll
            for (int tn = 0; tn < 2; ++tn)
                o[tm2][tn] = (f32x4){0.f, 0.f, 0.f, 0.f};
        #pragma unroll
        for (int kk = 0; kk < 2; ++kk) {
            int colk = (32 * kk + 8 * lg) * 2;
            bf16x8 bV[2];
            #pragma unroll
            for (int tn = 0; tn < 2; ++tn) {
                int cc = 32 * w + 16 * tn + lr;
                bV[tn] = *(const bf16x8*)(sVt + cc * 128 + (colk ^ gsw(cc)));
            }
            #pragma unroll
            for (int tq = 0; tq < 2; ++tq) {   // tq == target q-tile tm2
                int tmA = 2 * kk, tmB = 2 * kk + 1;
                int a0 = __shfl((int)pks[tmA][tq][0], srcA);
                int b0 = __shfl((int)pks[tmB][tq][0], srcA);
                int a1 = __shfl((int)pks[tmA][tq][1], srcA);
                int b1 = __shfl((int)pks[tmB][tq][1], srcA);
                int a2 = __shfl((int)pks[tmA][tq][0], srcB);
                int b2 = __shfl((int)pks[tmB][tq][0], srcB);
                int a3 = __shfl((int)pks[tmA][tq][1], srcB);
                int b3 = __shfl((int)pks[tmB][tq][1], srcB);
                int4 wv;
                wv.x = hi ? b0 : a0;
                wv.y = hi ? b1 : a1;
                wv.z = hi ? b2 : a2;
                wv.w = hi ? b3 : a3;
                bf16x8 aP = *(bf16x8*)&wv;
                #pragma unroll
                for (int tn = 0; tn < 2; ++tn)
                    o[tq][tn] = __builtin_amdgcn_mfma_f32_16x16x32_bf16(
                        aP, bV[tn], o[tq][tn], 0, 0, 0);
            }
        }

        // ---- direct coalesced float4 stores (4 consecutive tokens per reg) ----
        #pragma unroll
        for (int tm2 = 0; tm2 < 2; ++tm2)
            #pragma unroll
            for (int tn = 0; tn < 2; ++tn) {
                int ch = 32 * w + 16 * tn + lr;
                int tok = 32 * h + 16 * tm2 + 4 * lg;
                float4 ov;
                ov.x = o[tm2][tn][0];
                ov.y = o[tm2][tn][1];
                ov.z = o[tm2][tn][2];
                ov.w = o[tm2][tn][3];
                *(float4*)(out + xb + (long)ch * 16384 + tok) = ov;
            }

        if (wi == 0) __syncthreads();   // Bend: sVt reads done before restaging sX
    }
}

extern "C" void kernel_launch(void* const* d_in, const int* in_sizes, int n_in,
                              void* d_out, int out_size, void* d_ws, size_t ws_size,
                              hipStream_t stream) {
    const float* x  = (const float*)d_in[0];
    const float* Wq = (const float*)d_in[1];
    const float* bq = (const float*)d_in[2];
    const float* Wk = (const float*)d_in[3];
    const float* bk = (const float*)d_in[4];
    const float* Wv = (const float*)d_in[5];
    const float* bv = (const float*)d_in[6];
    const float* Bb = (const float*)d_in[7];
    float* out = (float*)d_out;
    ushort* wbf = (ushort*)d_ws;   // 3 x 128x128 bf16 = 96 KB

    wconv<<<64, 256, 0, stream>>>(Wq, Wk, Wv, wbf);
    attn_win<<<2048, 512, 0, stream>>>(x, wbf, bq, bk, bv, Bb, out);
}

// Round 8
// 147.824 us; speedup vs baseline: 1.6454x; 1.6454x over previous
//
#include <hip/hip_runtime.h>

// Windowed MHA, B=16 C=128 H=W=128, WINDOW=64, heads=4, d=32.
// 4096 blocks x 512 threads (8 waves; wave = (head w, token-half h)).
// bf16 MFMA 16x16x32, swapped QK^T (scores^T = mfma(K,Q)), softmax in
// registers, P per-wave in LDS (no barrier). LDS 48KB.
// R8 = R4 (last good) + fsw/gsw conflict-free swizzles (proven in R5).
// NO inline-asm cvt_pk (R6/R7 NaN; guide m240 says compiler handles packing).

typedef __attribute__((ext_vector_type(8))) short bf16x8;
typedef __attribute__((ext_vector_type(4))) float f32x4;

__device__ __forceinline__ ushort f2bf(float f) {
    unsigned u = __float_as_uint(f);
    u += 0x7FFF + ((u >> 16) & 1);          // RNE
    return (ushort)(u >> 16);
}
__device__ __forceinline__ unsigned pk2(float a, float b) {
    return (unsigned)f2bf(a) | ((unsigned)f2bf(b) << 16);
}

// 256B-row tiles (sX/sQ/sK): row bits 0-3 ^ bits 4-5 -> byte bits 4-7.
// Staging writes (16 lanes vary t4) and fragment reads (16 lanes vary lr)
// both land on 16 distinct 16B slots -> 2-way max (free).
__device__ __forceinline__ int fsw(int row) { return ((row ^ (row >> 4)) & 15) << 4; }
// 128B-row tiles (sVt): byte bits 4-6.
__device__ __forceinline__ int gsw(int row) { return ((row ^ (row >> 3)) & 7) << 4; }

__global__ void wconv(const float* __restrict__ Wq, const float* __restrict__ Wk,
                      const float* __restrict__ Wv, ushort* __restrict__ out) {
    int i = blockIdx.x * 256 + threadIdx.x;        // 16384 per matrix
    out[i]         = f2bf(Wq[i]);
    out[16384 + i] = f2bf(Wk[i]);
    out[32768 + i] = f2bf(Wv[i]);
}

__global__ __launch_bounds__(512, 4)
void attn_win(const float* __restrict__ x, const ushort* __restrict__ wbf,
              const float* __restrict__ bq, const float* __restrict__ bk,
              const float* __restrict__ bv, const float* __restrict__ Bb,
              float* __restrict__ out) {
    __shared__ __align__(16) char smem[49152];
    // R0 [0,16K): sX (staging) -> sVt after B1.5
    // R1 [16K,32K): sQ   R2 [32K,48K): sK
    // sP (4 heads x 8K) aliases R1+R2 after B3; per-wave-private rows.
    char* sX  = smem;
    char* sVt = smem;
    char* sQ  = smem + 16384;
    char* sK  = smem + 32768;
    char* sP  = smem + 16384;

    const int tid = threadIdx.x;
    const int wid = tid >> 6;        // 0..7
    const int w = wid & 3;           // head
    const int h = wid >> 2;          // token half (0..1)
    const int l = tid & 63;
    const int lr = l & 15;
    const int lg = (l >> 4) & 3;
    const int blk = blockIdx.x;
    const int b = blk >> 8, n = blk & 255;
    const long xbase = (long)b * 128 * 16384 + n * 64;

    // ---- stage X: channel-pair loads -> packed bf16x2 ds_write_b32 ----
    #pragma unroll
    for (int it = 0; it < 2; ++it) {
        int idx = it * 512 + tid;            // 1024 (cpair,t4) items
        int cp = idx >> 4, t4 = idx & 15;
        const float* px = x + xbase + (long)(2 * cp) * 16384 + t4 * 4;
        float4 v0 = *(const float4*)(px);
        float4 v1 = *(const float4*)(px + 16384);
        float a0[4] = {v0.x, v0.y, v0.z, v0.w};
        float a1[4] = {v1.x, v1.y, v1.z, v1.w};
        #pragma unroll
        for (int jj = 0; jj < 4; ++jj) {
            int t = t4 * 4 + jj;
            *(unsigned*)(sX + t * 256 + ((4 * cp) ^ fsw(t))) = pk2(a0[jj], a1[jj]);
        }
    }
    __syncthreads();   // B1

    // ---- A-fragments of X for this wave's 32 tokens ----
    bf16x8 aX[2][4];
    #pragma unroll
    for (int tmi = 0; tmi < 2; ++tmi) {
        int row = 32 * h + 16 * tmi + lr;
        #pragma unroll
        for (int kk = 0; kk < 4; ++kk) {
            int colb = (8 * lg + 32 * kk) * 2;
            aX[tmi][kk] = *(const bf16x8*)(sX + row * 256 + (colb ^ fsw(row)));
        }
    }
    __syncthreads();   // B1.5: all aX loaded before sVt overwrites sX

    // ---- projections: tokens 32h..+31, out-ch 32w..+31 ----
    const float* biases[3] = {bq, bk, bv};
    #pragma unroll
    for (int p = 0; p < 3; ++p) {
        const ushort* wp = wbf + p * 16384;
        f32x4 acc[2][2];
        #pragma unroll
        for (int tn = 0; tn < 2; ++tn) {
            float bias = biases[p][32 * w + 16 * tn + lr];
            #pragma unroll
            for (int tmi = 0; tmi < 2; ++tmi)
                acc[tmi][tn] = (f32x4){bias, bias, bias, bias};
        }
        // bW loaded per-kk: keeps peak VGPR pressure low (R3 spill lesson)
        #pragma unroll
        for (int kk = 0; kk < 4; ++kk) {
            bf16x8 bW[2];
            #pragma unroll
            for (int tn = 0; tn < 2; ++tn)
                bW[tn] = *(const bf16x8*)(wp + (32 * w + 16 * tn + lr) * 128 + 8 * lg + 32 * kk);
            #pragma unroll
            for (int tmi = 0; tmi < 2; ++tmi)
                #pragma unroll
                for (int tn = 0; tn < 2; ++tn)
                    acc[tmi][tn] = __builtin_amdgcn_mfma_f32_16x16x32_bf16(
                        aX[tmi][kk], bW[tn], acc[tmi][tn], 0, 0, 0);
        }
        if (p < 2) {
            // D: row tok = 32h+16tmi+4lg+r, col ch = 32w+16tn+lr
            char* dst = (p == 0) ? sQ : sK;
            #pragma unroll
            for (int tmi = 0; tmi < 2; ++tmi)
                #pragma unroll
                for (int tn = 0; tn < 2; ++tn)
                    #pragma unroll
                    for (int r = 0; r < 4; ++r) {
                        int row = 32 * h + 16 * tmi + 4 * lg + r;
                        int col = 32 * w + 16 * tn + lr;
                        *(ushort*)(dst + row * 256 + ((col * 2) ^ fsw(row)))
                            = f2bf(acc[tmi][tn][r]);
                    }
        } else {
            // V transposed sVt[c][tok]: r spans 4 consecutive tokens -> packed b64
            #pragma unroll
            for (int tmi = 0; tmi < 2; ++tmi)
                #pragma unroll
                for (int tn = 0; tn < 2; ++tn) {
                    int crow = 32 * w + 16 * tn + lr;
                    int tok0 = 32 * h + 16 * tmi + 4 * lg;
                    uint2 pk;
                    pk.x = pk2(acc[tmi][tn][0], acc[tmi][tn][1]);
                    pk.y = pk2(acc[tmi][tn][2], acc[tmi][tn][3]);
                    *(uint2*)(sVt + crow * 128 + ((2 * tok0) ^ gsw(crow))) = pk;
                }
        }
    }
    __syncthreads();   // B2

    // ---- scores^T = mfma(A=K, B=Q): D[k=16tm+4lg+r][q=32h+16tq+lr] ----
    bf16x8 aK[4], bQ[2];
    const int colqk = (32 * w + 8 * lg) * 2;
    #pragma unroll
    for (int tm = 0; tm < 4; ++tm) {
        int row = 16 * tm + lr;
        aK[tm] = *(const bf16x8*)(sK + row * 256 + (colqk ^ fsw(row)));
    }
    #pragma unroll
    for (int tq = 0; tq < 2; ++tq) {
        int row = 32 * h + 16 * tq + lr;
        bQ[tq] = *(const bf16x8*)(sQ + row * 256 + (colqk ^ fsw(row)));
    }
    f32x4 sc[4][2];
    #pragma unroll
    for (int tm = 0; tm < 4; ++tm)
        #pragma unroll
        for (int tq = 0; tq < 2; ++tq) {
            sc[tm][tq] = (f32x4){0.f, 0.f, 0.f, 0.f};
            sc[tm][tq] = __builtin_amdgcn_mfma_f32_16x16x32_bf16(
                aK[tm], bQ[tq], sc[tm][tq], 0, 0, 0);
        }

    // ---- softmax: k in-lane (16 vals) x lg across lanes; normalize at source ----
    const float scale = 0.17677669529663687f;   // 1/sqrt(32)
    const float L2E = 1.4426950408889634f;
    #pragma unroll
    for (int tq = 0; tq < 2; ++tq) {
        int q = 32 * h + 16 * tq + lr;
        #pragma unroll
        for (int tm = 0; tm < 4; ++tm) {
            float4 bb = *(const float4*)(Bb + q * 64 + 16 * tm + 4 * lg);
            sc[tm][tq][0] = sc[tm][tq][0] * scale + bb.x;
            sc[tm][tq][1] = sc[tm][tq][1] * scale + bb.y;
            sc[tm][tq][2] = sc[tm][tq][2] * scale + bb.z;
            sc[tm][tq][3] = sc[tm][tq][3] * scale + bb.w;
        }
        float mx = sc[0][tq][0];
        #pragma unroll
        for (int tm = 0; tm < 4; ++tm)
            #pragma unroll
            for (int r = 0; r < 4; ++r)
                mx = fmaxf(mx, sc[tm][tq][r]);
        mx = fmaxf(mx, __shfl_xor(mx, 16));
        mx = fmaxf(mx, __shfl_xor(mx, 32));
        float s = 0.f;
        #pragma unroll
        for (int tm = 0; tm < 4; ++tm)
            #pragma unroll
            for (int r = 0; r < 4; ++r) {
                float e = exp2f((sc[tm][tq][r] - mx) * L2E);
                sc[tm][tq][r] = e;
                s += e;
            }
        s += __shfl_xor(s, 16);
        s += __shfl_xor(s, 32);
        float rs = 1.0f / s;
        #pragma unroll
        for (int tm = 0; tm < 4; ++tm)
            #pragma unroll
            for (int r = 0; r < 4; ++r)
                sc[tm][tq][r] *= rs;
    }
    __syncthreads();   // B3: sQ/sK frag reads done before sP overwrite

    // ---- P (normalized, bf16) -> per-wave-private sP rows, packed b64 ----
    char* sPw = sP + w * 8192;
    #pragma unroll
    for (int tm = 0; tm < 4; ++tm)
        #pragma unroll
        for (int tq = 0; tq < 2; ++tq) {
            int q = 32 * h + 16 * tq + lr;
            int k0 = 16 * tm + 4 * lg;
            uint2 pk;
            pk.x = pk2(sc[tm][tq][0], sc[tm][tq][1]);
            pk.y = pk2(sc[tm][tq][2], sc[tm][tq][3]);
            *(uint2*)(sPw + q * 128 + ((2 * k0) ^ ((q & 7) << 4))) = pk;
        }
    // same-wave write->read: compiler orders via lgkmcnt, no barrier needed

    // ---- out = P . V : q 32 (2 tiles), d 32 (2 tiles), K = 64 keys ----
    f32x4 o[2][2];
    #pragma unroll
    for (int tm2 = 0; tm2 < 2; ++tm2)
        #pragma unroll
        for (int tn = 0; tn < 2; ++tn)
            o[tm2][tn] = (f32x4){0.f, 0.f, 0.f, 0.f};
    #pragma unroll
    for (int kk = 0; kk < 2; ++kk) {
        bf16x8 aP[2], bV[2];
        int colk = (32 * kk + 8 * lg) * 2;
        #pragma unroll
        for (int tm2 = 0; tm2 < 2; ++tm2) {
            int q = 32 * h + 16 * tm2 + lr;
            aP[tm2] = *(const bf16x8*)(sPw + q * 128 + (colk ^ ((q & 7) << 4)));
        }
        #pragma unroll
        for (int tn = 0; tn < 2; ++tn) {
            int cc = 32 * w + 16 * tn + lr;
            bV[tn] = *(const bf16x8*)(sVt + cc * 128 + (colk ^ gsw(cc)));
        }
        #pragma unroll
        for (int tm2 = 0; tm2 < 2; ++tm2)
            #pragma unroll
            for (int tn = 0; tn < 2; ++tn)
                o[tm2][tn] = __builtin_amdgcn_mfma_f32_16x16x32_bf16(
                    aP[tm2], bV[tn], o[tm2][tn], 0, 0, 0);
    }

    // ---- direct coalesced float4 stores (4 consecutive tokens per reg) ----
    #pragma unroll
    for (int tm2 = 0; tm2 < 2; ++tm2)
        #pragma unroll
        for (int tn = 0; tn < 2; ++tn) {
            int ch = 32 * w + 16 * tn + lr;
            int tok = 32 * h + 16 * tm2 + 4 * lg;
            float4 ov;
            ov.x = o[tm2][tn][0];
            ov.y = o[tm2][tn][1];
            ov.z = o[tm2][tn][2];
            ov.w = o[tm2][tn][3];
            *(float4*)(out + xbase + (long)ch * 16384 + tok) = ov;
        }
}

extern "C" void kernel_launch(void* const* d_in, const int* in_sizes, int n_in,
                              void* d_out, int out_size, void* d_ws, size_t ws_size,
                              hipStream_t stream) {
    const float* x  = (const float*)d_in[0];
    const float* Wq = (const float*)d_in[1];
    const float* bq = (const float*)d_in[2];
    const float* Wk = (const float*)d_in[3];
    const float* bk = (const float*)d_in[4];
    const float* Wv = (const float*)d_in[5];
    const float* bv = (const float*)d_in[6];
    const float* Bb = (const float*)d_in[7];
    float* out = (float*)d_out;
    ushort* wbf = (ushort*)d_ws;   // 3 x 128x128 bf16 = 96 KB

    wconv<<<64, 256, 0, stream>>>(Wq, Wk, Wv, wbf);
    attn_win<<<4096, 512, 0, stream>>>(x, wbf, bq, bk, bv, Bb, out);
}